// Round 4
// baseline (207.596 us; speedup 1.0000x reference)
//
#include <hip/hip_runtime.h>
#include <cstdint>

#define NBATCH 4
#define NPATCH 4096
#define FDIM   256
#define MAXC   5
#define BM 64
#define BN 64
#define NSPLIT 4
#define SPLITITERS (NPATCH / BN / NSPLIT)   /* 16 col-tiles per block */
#define SCALE  14.285714285714286f          /* 1/T, T=0.07 */
#define SCALE2 20.609929006188747f          /* (1/T) * log2(e) */
#define LN2F   0.6931471805599453f
#define NEGH  -1.0e38f
#define NROWS (NBATCH * NPATCH)

typedef __attribute__((ext_vector_type(8))) short short8;   // 8 bf16 (4 VGPRs)
typedef __attribute__((ext_vector_type(4))) float f32x4;

__device__ __forceinline__ float fexp2(float x) { return __builtin_amdgcn_exp2f(x); }
__device__ __forceinline__ float flog2(float x) { return __builtin_amdgcn_logf(x); }  // v_log_f32 = log2

__device__ __forceinline__ unsigned short f2bf(float f) {
  uint32_t u = __builtin_bit_cast(uint32_t, f);
  u = (u + 0x7FFFu + ((u >> 16) & 1u)) >> 16;   // RNE
  return (unsigned short)u;
}

// ---------- fused: tgt f32->bf16 convert + exact f32 positive logits ----------
__global__ __launch_bounds__(256) void k_cvtpos(const float* __restrict__ src,
                                                const float* __restrict__ tgt,
                                                unsigned short* __restrict__ tgtb,
                                                float* __restrict__ pos) {
  int row  = blockIdx.x * 4 + (threadIdx.x >> 6);
  int lane = threadIdx.x & 63;
  float4 va = ((const float4*)src)[(size_t)row * 64 + lane];
  float4 vb = ((const float4*)tgt)[(size_t)row * 64 + lane];
  ushort4 o;
  o.x = f2bf(vb.x); o.y = f2bf(vb.y); o.z = f2bf(vb.z); o.w = f2bf(vb.w);
  ((ushort4*)tgtb)[(size_t)row * 64 + lane] = o;
  float d = va.x * vb.x + va.y * vb.y + va.z * vb.z + va.w * vb.w;
#pragma unroll
  for (int off = 32; off > 0; off >>= 1) d += __shfl_xor(d, off, 64);
  if (lane == 0) pos[row] = d * SCALE;
}

// ---------------- main fused GEMM + online stats (column-split) ----------------
// grid = 1024; XCD-swizzled so the 8 blocks per XCD within a group share one B-slice.
// A fragments pre-scaled by (1/T)*log2e, converted to bf16 once, live in regs for K=256.
// Stats in log2 domain, branchless online update.
__global__ __launch_bounds__(256) void k_main(const float* __restrict__ src,
                                              const unsigned short* __restrict__ tgtb,
                                              const int* __restrict__ classes,
                                              float* __restrict__ pm,
                                              float* __restrict__ ps,
                                              float* __restrict__ pmn) {
  __shared__ uint4 sB[BN * 33];                  // 64 rows x (32 chunks + 1 pad)
  __shared__ float redm[2][BM], reds[2][BM], redn[2][BM];

  // XCD-aware swizzle: blk -> (b, split, rb) with rb grouped per XCD so resident
  // blocks on an XCD share a 512KB B-slice in its L2.
  const int blk   = blockIdx.x;
  const int xcd   = blk & 7;
  const int g     = blk >> 3;           // 0..127
  const int group = g >> 3;             // 0..15  -> (b, split)
  const int pos_  = g & 7;              // 0..7
  const int b     = group >> 2;
  const int split = group & 3;
  const int rb    = xcd * 8 + pos_;     // 0..63
  const int rowstart = b * NPATCH + rb * BM;
  const int tid = threadIdx.x;
  const int w = tid >> 6, lane = tid & 63, q = lane >> 4, l4 = lane & 15;
  const int rh = w >> 1, ch = w & 1;

  // A fragments: f32 -> (pre-scaled) bf16 once (invariant across col tiles)
  uint4 afr[2][8];
  const float4* s4 = (const float4*)src;
#pragma unroll
  for (int rt = 0; rt < 2; ++rt) {
    int row = rowstart + rh * 32 + rt * 16 + l4;
#pragma unroll
    for (int ks = 0; ks < 8; ++ks) {
      float4 fa = s4[(size_t)row * 64 + ks * 8 + q * 2];
      float4 fb = s4[(size_t)row * 64 + ks * 8 + q * 2 + 1];
      union { ushort4 h[2]; uint4 u; } pk;
      pk.h[0].x = f2bf(fa.x * SCALE2); pk.h[0].y = f2bf(fa.y * SCALE2);
      pk.h[0].z = f2bf(fa.z * SCALE2); pk.h[0].w = f2bf(fa.w * SCALE2);
      pk.h[1].x = f2bf(fb.x * SCALE2); pk.h[1].y = f2bf(fb.y * SCALE2);
      pk.h[1].z = f2bf(fb.z * SCALE2); pk.h[1].w = f2bf(fb.w * SCALE2);
      afr[rt][ks] = pk.u;
    }
  }

  int rcls[2][4];
#pragma unroll
  for (int rt = 0; rt < 2; ++rt)
#pragma unroll
    for (int r = 0; r < 4; ++r)
      rcls[rt][r] = classes[rowstart + rh * 32 + rt * 16 + q * 4 + r];

  float m_[2][4], s_[2][4], mn_[2][4];
#pragma unroll
  for (int rt = 0; rt < 2; ++rt)
#pragma unroll
    for (int r = 0; r < 4; ++r) { m_[rt][r] = -INFINITY; s_[rt][r] = 0.f; mn_[rt][r] = INFINITY; }

  const uint4* tgv = (const uint4*)tgtb;         // row stride = 32 uint4
  const int colbase = b * NPATCH + split * (NPATCH / NSPLIT);

  for (int cit = 0; cit < SPLITITERS; ++cit) {
    // stage B tile (64 rows x 512B), coalesced 16B chunks
#pragma unroll
    for (int i = 0; i < 8; ++i) {
      int chunk = i * 256 + tid;
      int rr = chunk >> 5, cc = chunk & 31;
      sB[rr * 33 + cc] = tgv[(size_t)(colbase + cit * BN + rr) * 32 + cc];
    }
    __syncthreads();

    int c0 = classes[colbase + cit * BN + ch * 32 + l4];
    int c1 = classes[colbase + cit * BN + ch * 32 + 16 + l4];

    f32x4 acc[2][2];
#pragma unroll
    for (int rt = 0; rt < 2; ++rt)
#pragma unroll
      for (int ct = 0; ct < 2; ++ct) { f32x4 z = {0.f, 0.f, 0.f, 0.f}; acc[rt][ct] = z; }

#pragma unroll
    for (int ks = 0; ks < 8; ++ks) {
      short8 b0 = __builtin_bit_cast(short8, sB[(ch * 32 + l4) * 33 + ks * 4 + q]);
      short8 b1 = __builtin_bit_cast(short8, sB[(ch * 32 + 16 + l4) * 33 + ks * 4 + q]);
#pragma unroll
      for (int rt = 0; rt < 2; ++rt) {
        short8 a = __builtin_bit_cast(short8, afr[rt][ks]);
        acc[rt][0] = __builtin_amdgcn_mfma_f32_16x16x32_bf16(a, b0, acc[rt][0], 0, 0, 0);
        acc[rt][1] = __builtin_amdgcn_mfma_f32_16x16x32_bf16(a, b1, acc[rt][1], 0, 0, 0);
      }
    }

    // online per-lane stats, log2 domain (acc already scaled), branchless
#pragma unroll
    for (int rt = 0; rt < 2; ++rt) {
#pragma unroll
      for (int r = 0; r < 4; ++r) {
        float x0 = acc[rt][0][r];
        float x1 = acc[rt][1][r];
        int rc = rcls[rt][r];
        bool sm0 = (c0 == rc), sm1 = (c1 == rc);
        mn_[rt][r] = fminf(mn_[rt][r], sm0 ? INFINITY : x0);
        mn_[rt][r] = fminf(mn_[rt][r], sm1 ? INFINITY : x1);
        float y0 = sm0 ? NEGH : x0;
        float y1 = sm1 ? NEGH : x1;
        float nm = fmaxf(m_[rt][r], fmaxf(y0, y1));
        s_[rt][r] = s_[rt][r] * fexp2(m_[rt][r] - nm)
                  + fexp2(y0 - nm) + fexp2(y1 - nm);
        m_[rt][r] = nm;
      }
    }
    __syncthreads();
  }

  // butterfly merge across the 16 col-lanes of each quad
#pragma unroll
  for (int off = 1; off < 16; off <<= 1) {
#pragma unroll
    for (int rt = 0; rt < 2; ++rt)
#pragma unroll
      for (int r = 0; r < 4; ++r) {
        float om = __shfl_xor(m_[rt][r], off, 64);
        float os = __shfl_xor(s_[rt][r], off, 64);
        float on = __shfl_xor(mn_[rt][r], off, 64);
        float nm = fmaxf(m_[rt][r], om);
        s_[rt][r] = s_[rt][r] * fexp2(m_[rt][r] - nm) + os * fexp2(om - nm);
        m_[rt][r] = nm;
        mn_[rt][r] = fminf(mn_[rt][r], on);
      }
  }

  if (l4 == 0) {
#pragma unroll
    for (int rt = 0; rt < 2; ++rt)
#pragma unroll
      for (int r = 0; r < 4; ++r) {
        int li = rh * 32 + rt * 16 + q * 4 + r;
        redm[ch][li] = m_[rt][r];
        reds[ch][li] = s_[rt][r];
        redn[ch][li] = mn_[rt][r];
      }
  }
  __syncthreads();
  if (tid < BM) {
    float m0 = redm[0][tid], m1 = redm[1][tid];
    float nm = fmaxf(m0, m1);
    float s  = reds[0][tid] * fexp2(m0 - nm) + reds[1][tid] * fexp2(m1 - nm);
    size_t o = (size_t)split * NROWS + rowstart + tid;
    pm[o]  = nm;                                  // log2 domain
    ps[o]  = s;
    pmn[o] = fminf(redn[0][tid], redn[1][tid]);   // log2 domain
  }
}

// ---------------- per-batch: counts, stable ranks, class-min ----------------
__global__ __launch_bounds__(256) void k_scan(const int* __restrict__ classes,
                                              const float* __restrict__ pmn,
                                              int* __restrict__ outpos,
                                              int* __restrict__ counts,
                                              float* __restrict__ classmin) {
  __shared__ int sa[MAXC * 256];
  __shared__ int sb2[MAXC * 256];
  __shared__ float smn[MAXC * 256];
  int b = blockIdx.x, t = threadIdx.x;
  int base = b * NPATCH + t * 16;
  int cv[16]; float mv[16];
#pragma unroll
  for (int e = 0; e < 16; ++e) {
    cv[e] = classes[base + e];
    float mm = INFINITY;
#pragma unroll
    for (int s = 0; s < NSPLIT; ++s) mm = fminf(mm, pmn[(size_t)s * NROWS + base + e]);
    mv[e] = mm * LN2F;                            // back to natural (/T) domain
  }
  int cnt[MAXC]; float cmn[MAXC];
#pragma unroll
  for (int c = 0; c < MAXC; ++c) {
    cnt[c] = 0; cmn[c] = INFINITY;
#pragma unroll
    for (int e = 0; e < 16; ++e)
      if (cv[e] == c) { cnt[c]++; cmn[c] = fminf(cmn[c], mv[e]); }
  }
#pragma unroll
  for (int c = 0; c < MAXC; ++c) { sa[c * 256 + t] = cnt[c]; smn[c * 256 + t] = cmn[c]; }
  __syncthreads();

  int* rp = sa; int* wp = sb2;
  for (int d = 1; d < 256; d <<= 1) {            // Hillis-Steele inclusive scan
#pragma unroll
    for (int c = 0; c < MAXC; ++c) {
      int v = rp[c * 256 + t];
      if (t >= d) v += rp[c * 256 + t - d];
      wp[c * 256 + t] = v;
    }
    __syncthreads();
    int* tmp = rp; rp = wp; wp = tmp;
  }
  for (int d = 128; d > 0; d >>= 1) {            // per-class min tree
    if (t < d) {
#pragma unroll
      for (int c = 0; c < MAXC; ++c)
        smn[c * 256 + t] = fminf(smn[c * 256 + t], smn[c * 256 + t + d]);
    }
    __syncthreads();
  }

  int tot[MAXC], excl[MAXC], off[MAXC + 1];
  off[0] = 0;
#pragma unroll
  for (int c = 0; c < MAXC; ++c) {
    tot[c]  = rp[c * 256 + 255];
    excl[c] = rp[c * 256 + t] - cnt[c];
    off[c + 1] = off[c] + tot[c];
  }
#pragma unroll
  for (int c = 0; c < MAXC; ++c) {
    int r = off[c] + excl[c];
#pragma unroll
    for (int e = 0; e < 16; ++e)
      if (cv[e] == c) { outpos[base + e] = r; r++; }
  }
  if (t < MAXC) { counts[b * MAXC + t] = tot[t]; classmin[b * MAXC + t] = smn[t * 256 + 0]; }
}

// ---------------- final: merge split lse partials + combine + scatter ----------------
__global__ __launch_bounds__(256) void k_final(const int* __restrict__ classes,
                                               const float* __restrict__ pos,
                                               const float* __restrict__ pm,
                                               const float* __restrict__ ps,
                                               const int* __restrict__ outpos,
                                               const int* __restrict__ counts,
                                               const float* __restrict__ classmin,
                                               float* __restrict__ out) {
  int n = blockIdx.x * 256 + threadIdx.x;
  int b = n >> 12;
  int c = classes[n];
  float ps_ = pos[n];

  // merge NSPLIT partial (m,s) in log2 domain
  float mm[NSPLIT], ss[NSPLIT];
#pragma unroll
  for (int s = 0; s < NSPLIT; ++s) {
    mm[s] = pm[(size_t)s * NROWS + n];
    ss[s] = ps[(size_t)s * NROWS + n];
  }
  float M2 = fmaxf(fmaxf(mm[0], mm[1]), fmaxf(mm[2], mm[3]));
  float S2 = ss[0] * fexp2(mm[0] - M2) + ss[1] * fexp2(mm[1] - M2)
           + ss[2] * fexp2(mm[2] - M2) + ss[3] * fexp2(mm[3] - M2);
  float ln = (S2 > 0.f) ? (M2 + flog2(S2)) * LN2F : -INFINITY;

  int cnt  = counts[b * MAXC + c];
  float cm = classmin[b * MAXC + c];
  float sm = fminf(cm, -10.0f * SCALE);          // min(class_min, NEG_FILL)/T, nat domain
  int npad = cnt - 1;
  float pt = (npad > 0) ? (logf((float)npad) + sm) : -INFINITY;
  float M = fmaxf(ps_, fmaxf(ln, pt));
  float lse = M + logf(expf(ps_ - M) + expf(ln - M) + expf(pt - M));
  out[b * NPATCH + outpos[n]] = lse - ps_;
}

extern "C" void kernel_launch(void* const* d_in, const int* in_sizes, int n_in,
                              void* d_out, int out_size, void* d_ws, size_t ws_size,
                              hipStream_t stream) {
  const float* src = (const float*)d_in[0];
  const float* tgt = (const float*)d_in[1];
  const int* cls   = (const int*)d_in[2];
  float* out = (float*)d_out;

  char* ws = (char*)d_ws;
  unsigned short* tgtb = (unsigned short*)(ws);            // 8,388,608 B
  float* pos      = (float*)(ws + 8388608);                //    65,536 B
  float* pm       = (float*)(ws + 8454144);                //   262,144 B
  float* ps       = (float*)(ws + 8716288);                //   262,144 B
  float* pmn      = (float*)(ws + 8978432);                //   262,144 B
  int*   outpos   = (int*)  (ws + 9240576);                //    65,536 B
  int*   counts   = (int*)  (ws + 9306112);                //        80 B
  float* classmin = (float*)(ws + 9306192);                //        80 B

  k_cvtpos<<<NROWS / 4, 256, 0, stream>>>(src, tgt, tgtb, pos);
  k_main<<<NBATCH * (NPATCH / BM) * NSPLIT, 256, 0, stream>>>(src, tgtb, cls, pm, ps, pmn);
  k_scan<<<NBATCH, 256, 0, stream>>>(cls, pmn, outpos, counts, classmin);
  k_final<<<NROWS / 256, 256, 0, stream>>>(cls, pos, pm, ps, outpos, counts, classmin, out);
}

// Round 5
// 162.430 us; speedup vs baseline: 1.2781x; 1.2781x over previous
//
#include <hip/hip_runtime.h>
#include <cstdint>

#define NBATCH 4
#define NPATCH 4096
#define MAXC   5
#define BM 64
#define BN 64
#define NSPLIT 4
#define NCIT (NPATCH / BN / NSPLIT)         /* 16 col-tiles per block */
#define SCALE  14.285714285714286f          /* 1/T, T=0.07 */
#define SCALE2 20.609929006188747f          /* (1/T) * log2(e) */
#define LN2F   0.6931471805599453f
#define NEGH  -1.0e38f
#define NROWS (NBATCH * NPATCH)
#define SBYTES 16384                        /* one stage buffer: 64 cols x 128 k x 2B */

typedef __attribute__((ext_vector_type(8))) short short8;   // 8 bf16 (4 VGPRs)
typedef __attribute__((ext_vector_type(4))) float f32x4;

__device__ __forceinline__ float fexp2(float x) { return __builtin_amdgcn_exp2f(x); }
__device__ __forceinline__ float flog2(float x) { return __builtin_amdgcn_logf(x); }  // v_log_f32 = log2

__device__ __forceinline__ unsigned short f2bf(float f) {
  uint32_t u = __builtin_bit_cast(uint32_t, f);
  u = (u + 0x7FFFu + ((u >> 16) & 1u)) >> 16;   // RNE
  return (unsigned short)u;
}

// async global -> LDS DMA, 16B per lane; LDS dest = wave-uniform base + lane*16
__device__ __forceinline__ void dma16(const void* g, void* l) {
  __builtin_amdgcn_global_load_lds(
      (const __attribute__((address_space(1))) void*)g,
      (__attribute__((address_space(3))) void*)l, 16, 0, 0);
}

// ---------- fused: tgt f32->bf16 convert + exact f32 positive logits ----------
__global__ __launch_bounds__(256) void k_cvtpos(const float* __restrict__ src,
                                                const float* __restrict__ tgt,
                                                unsigned short* __restrict__ tgtb,
                                                float* __restrict__ pos) {
  int row  = blockIdx.x * 4 + (threadIdx.x >> 6);
  int lane = threadIdx.x & 63;
  float4 va = ((const float4*)src)[(size_t)row * 64 + lane];
  float4 vb = ((const float4*)tgt)[(size_t)row * 64 + lane];
  ushort4 o;
  o.x = f2bf(vb.x); o.y = f2bf(vb.y); o.z = f2bf(vb.z); o.w = f2bf(vb.w);
  ((ushort4*)tgtb)[(size_t)row * 64 + lane] = o;
  float d = va.x * vb.x + va.y * vb.y + va.z * vb.z + va.w * vb.w;
#pragma unroll
  for (int off = 32; off > 0; off >>= 1) d += __shfl_xor(d, off, 64);
  if (lane == 0) pos[row] = d * SCALE;
}

// ---------------- main fused GEMM + online stats ----------------
// Linear block map (split = blk&3 -> XCD-local B slice via HW round-robin).
// Double-buffered async DMA staging: stage = 64 cols x K/2, 2 x 16KB LDS.
// XOR bank swizzle: physical chunk p = logical chunk ^ (row&7) (2-way conflicts only).
// A fragments pre-scaled by (1/T)*log2e, bf16, in registers for all K=256.
__global__ __launch_bounds__(256) void k_main(const float* __restrict__ src,
                                              const unsigned short* __restrict__ tgtb,
                                              const int* __restrict__ classes,
                                              float* __restrict__ pm,
                                              float* __restrict__ ps,
                                              float* __restrict__ pmn) {
  __shared__ uint4 sS[2 * SBYTES / 16];          // 32 KB, two ping-pong stage buffers
  __shared__ float redm[2][BM], reds[2][BM], redn[2][BM];

  const int blk   = blockIdx.x;
  const int split = blk & (NSPLIT - 1);
  const int rbk   = blk >> 2;
  const int b     = rbk >> 6;
  const int rb    = rbk & 63;
  const int rowstart = b * NPATCH + rb * BM;
  const int tid = threadIdx.x;
  const int w = tid >> 6, lane = tid & 63, q = lane >> 4, l4 = lane & 15;
  const int rh = w >> 1, ch = w & 1;
  const int colbase = b * NPATCH + split * (NPATCH / NSPLIT);

  char* smem = (char*)sS;
  const char* tg8 = (const char*)tgtb;

  // ---- DMA addressing (per lane): inst i covers rows w*16+4i..+3 of the stage tile.
  // lane l -> row +(l>>4), physical chunk slot (l&15); global chunk cc = (l&15) ^ (row&7).
  const int r2  = lane >> 4;
  const int c16 = lane & 15;
  const size_t gbase = (size_t)(colbase + w * 16 + r2) * 512 + (size_t)((c16 ^ r2) * 16);

#define ISSUE(cit_, kh_, bb_)                                                        \
  {                                                                                  \
    _Pragma("unroll")                                                                \
    for (int i = 0; i < 4; ++i) {                                                    \
      size_t g = (gbase + (size_t)(cit_) * 32768 + (size_t)((kh_) * 256) +           \
                  (size_t)(i * 2048)) ^ (size_t)((i & 1) << 6);                      \
      dma16(tg8 + g, smem + (bb_) * SBYTES + w * 4096 + i * 1024);                   \
    }                                                                                \
  }

  // prologue: start DMA for stage (0,0) before the (long) A-fragment setup
  ISSUE(0, 0, 0);

  // ---- A fragments: f32 -> pre-scaled bf16 once (invariant across col tiles)
  uint4 afr[2][8];
  const float4* s4 = (const float4*)src;
#pragma unroll
  for (int rt = 0; rt < 2; ++rt) {
    int row = rowstart + rh * 32 + rt * 16 + l4;
#pragma unroll
    for (int ks = 0; ks < 8; ++ks) {
      float4 fa = s4[(size_t)row * 64 + ks * 8 + q * 2];
      float4 fb = s4[(size_t)row * 64 + ks * 8 + q * 2 + 1];
      union { ushort4 h[2]; uint4 u; } pk;
      pk.h[0].x = f2bf(fa.x * SCALE2); pk.h[0].y = f2bf(fa.y * SCALE2);
      pk.h[0].z = f2bf(fa.z * SCALE2); pk.h[0].w = f2bf(fa.w * SCALE2);
      pk.h[1].x = f2bf(fb.x * SCALE2); pk.h[1].y = f2bf(fb.y * SCALE2);
      pk.h[1].z = f2bf(fb.z * SCALE2); pk.h[1].w = f2bf(fb.w * SCALE2);
      afr[rt][ks] = pk.u;
    }
  }

  int rcls[2][4];
#pragma unroll
  for (int rt = 0; rt < 2; ++rt)
#pragma unroll
    for (int r = 0; r < 4; ++r)
      rcls[rt][r] = classes[rowstart + rh * 32 + rt * 16 + q * 4 + r];

  float m_[2][4], s_[2][4], mn_[2][4];
#pragma unroll
  for (int rt = 0; rt < 2; ++rt)
#pragma unroll
    for (int r = 0; r < 4; ++r) { m_[rt][r] = -INFINITY; s_[rt][r] = 0.f; mn_[rt][r] = INFINITY; }

  // ---- ds_read addressing: lane (q,l4) reads col tile rows ch*32+ct*16+l4,
  // logical chunk c = ksl*4+q  ->  physical p = c ^ (l4&7)
  const int kx = (l4 >> 2) & 1;
  const int qq = q ^ (l4 & 3);
  const int bbase0 = (ch * 32 + l4) * 256 + qq * 16;
  const int bbase1 = bbase0 + 4096;              // +16 rows

  int bb = 0;
  for (int cit = 0; cit < NCIT; ++cit) {
    int c0 = classes[colbase + cit * BN + ch * 32 + l4];
    int c1 = classes[colbase + cit * BN + ch * 32 + 16 + l4];

    f32x4 acc[2][2];
#pragma unroll
    for (int rt = 0; rt < 2; ++rt)
#pragma unroll
      for (int ct = 0; ct < 2; ++ct) { f32x4 z = {0.f, 0.f, 0.f, 0.f}; acc[rt][ct] = z; }

#pragma unroll
    for (int kh = 0; kh < 2; ++kh) {
      __syncthreads();                           // DMA(cur) landed; prev compute done
      // issue DMA for the next stage into the other buffer
      if (kh == 0) {
        ISSUE(cit, 1, bb ^ 1);
      } else if (cit + 1 < NCIT) {
        ISSUE(cit + 1, 0, bb ^ 1);
      }
      // compute current stage from buffer bb
#pragma unroll
      for (int ksl = 0; ksl < 4; ++ksl) {
        int off = bb * SBYTES + ((ksl ^ kx) << 6);
        short8 b0 = __builtin_bit_cast(short8, *(const uint4*)(smem + off + bbase0));
        short8 b1 = __builtin_bit_cast(short8, *(const uint4*)(smem + off + bbase1));
#pragma unroll
        for (int rt = 0; rt < 2; ++rt) {
          short8 a = __builtin_bit_cast(short8, afr[rt][kh * 4 + ksl]);
          acc[rt][0] = __builtin_amdgcn_mfma_f32_16x16x32_bf16(a, b0, acc[rt][0], 0, 0, 0);
          acc[rt][1] = __builtin_amdgcn_mfma_f32_16x16x32_bf16(a, b1, acc[rt][1], 0, 0, 0);
        }
      }
      bb ^= 1;
    }

    // online per-lane stats, log2 domain (acc already scaled), branchless.
    // Runs while next stage's DMA is in flight.
#pragma unroll
    for (int rt = 0; rt < 2; ++rt) {
#pragma unroll
      for (int r = 0; r < 4; ++r) {
        float x0 = acc[rt][0][r];
        float x1 = acc[rt][1][r];
        int rc = rcls[rt][r];
        bool sm0 = (c0 == rc), sm1 = (c1 == rc);
        mn_[rt][r] = fminf(mn_[rt][r], sm0 ? INFINITY : x0);
        mn_[rt][r] = fminf(mn_[rt][r], sm1 ? INFINITY : x1);
        float y0 = sm0 ? NEGH : x0;
        float y1 = sm1 ? NEGH : x1;
        float nm = fmaxf(m_[rt][r], fmaxf(y0, y1));
        s_[rt][r] = s_[rt][r] * fexp2(m_[rt][r] - nm)
                  + fexp2(y0 - nm) + fexp2(y1 - nm);
        m_[rt][r] = nm;
      }
    }
  }

  // butterfly merge across the 16 col-lanes of each quad
#pragma unroll
  for (int off = 1; off < 16; off <<= 1) {
#pragma unroll
    for (int rt = 0; rt < 2; ++rt)
#pragma unroll
      for (int r = 0; r < 4; ++r) {
        float om = __shfl_xor(m_[rt][r], off, 64);
        float os = __shfl_xor(s_[rt][r], off, 64);
        float on = __shfl_xor(mn_[rt][r], off, 64);
        float nm = fmaxf(m_[rt][r], om);
        s_[rt][r] = s_[rt][r] * fexp2(m_[rt][r] - nm) + os * fexp2(om - nm);
        m_[rt][r] = nm;
        mn_[rt][r] = fminf(mn_[rt][r], on);
      }
  }

  if (l4 == 0) {
#pragma unroll
    for (int rt = 0; rt < 2; ++rt)
#pragma unroll
      for (int r = 0; r < 4; ++r) {
        int li = rh * 32 + rt * 16 + q * 4 + r;
        redm[ch][li] = m_[rt][r];
        reds[ch][li] = s_[rt][r];
        redn[ch][li] = mn_[rt][r];
      }
  }
  __syncthreads();
  if (tid < BM) {
    float m0 = redm[0][tid], m1 = redm[1][tid];
    float nm = fmaxf(m0, m1);
    float s  = reds[0][tid] * fexp2(m0 - nm) + reds[1][tid] * fexp2(m1 - nm);
    size_t o = (size_t)split * NROWS + rowstart + tid;
    pm[o]  = nm;                                  // log2 domain
    ps[o]  = s;
    pmn[o] = fminf(redn[0][tid], redn[1][tid]);   // log2 domain
  }
#undef ISSUE
}

// ------- fused per-batch scan (counts, stable ranks, class-min) + final combine -------
__global__ __launch_bounds__(256) void k_post(const int* __restrict__ classes,
                                              const float* __restrict__ pos,
                                              const float* __restrict__ pm,
                                              const float* __restrict__ ps,
                                              const float* __restrict__ pmn,
                                              float* __restrict__ out) {
  __shared__ int sa[MAXC * 256];
  __shared__ int sb2[MAXC * 256];
  __shared__ float smn[MAXC * 256];
  int b = blockIdx.x, t = threadIdx.x;
  int base = b * NPATCH + t * 16;
  int cv[16]; float mv[16];
#pragma unroll
  for (int e = 0; e < 16; ++e) {
    cv[e] = classes[base + e];
    float mm = INFINITY;
#pragma unroll
    for (int s = 0; s < NSPLIT; ++s) mm = fminf(mm, pmn[(size_t)s * NROWS + base + e]);
    mv[e] = mm * LN2F;                            // back to natural (/T) domain
  }
  int cnt[MAXC]; float cmn[MAXC];
#pragma unroll
  for (int c = 0; c < MAXC; ++c) {
    cnt[c] = 0; cmn[c] = INFINITY;
#pragma unroll
    for (int e = 0; e < 16; ++e)
      if (cv[e] == c) { cnt[c]++; cmn[c] = fminf(cmn[c], mv[e]); }
  }
#pragma unroll
  for (int c = 0; c < MAXC; ++c) { sa[c * 256 + t] = cnt[c]; smn[c * 256 + t] = cmn[c]; }
  __syncthreads();

  int* rp = sa; int* wp = sb2;
  for (int d = 1; d < 256; d <<= 1) {            // Hillis-Steele inclusive scan (8 iters)
#pragma unroll
    for (int c = 0; c < MAXC; ++c) {
      int v = rp[c * 256 + t];
      if (t >= d) v += rp[c * 256 + t - d];
      wp[c * 256 + t] = v;
    }
    __syncthreads();
    int* tmp = rp; rp = wp; wp = tmp;
  }
  for (int d = 128; d > 0; d >>= 1) {            // per-class min tree
    if (t < d) {
#pragma unroll
      for (int c = 0; c < MAXC; ++c)
        smn[c * 256 + t] = fminf(smn[c * 256 + t], smn[c * 256 + t + d]);
    }
    __syncthreads();
  }

  int tot[MAXC], excl[MAXC], off[MAXC + 1];
  float cmins[MAXC];
  off[0] = 0;
#pragma unroll
  for (int c = 0; c < MAXC; ++c) {
    tot[c]   = rp[c * 256 + 255];
    excl[c]  = rp[c * 256 + t] - cnt[c];
    cmins[c] = smn[c * 256 + 0];
    off[c + 1] = off[c] + tot[c];
  }
  int opos[16];
#pragma unroll
  for (int c = 0; c < MAXC; ++c) {
    int r = off[c] + excl[c];
#pragma unroll
    for (int e = 0; e < 16; ++e)
      if (cv[e] == c) { opos[e] = r; r++; }
  }

  // final combine + scatter for this thread's 16 rows
#pragma unroll
  for (int e = 0; e < 16; ++e) {
    int n = base + e;
    int c = cv[e];
    float ps_ = pos[n];
    float mm[NSPLIT], ss[NSPLIT];
#pragma unroll
    for (int s = 0; s < NSPLIT; ++s) {
      mm[s] = pm[(size_t)s * NROWS + n];
      ss[s] = ps[(size_t)s * NROWS + n];
    }
    float M2 = fmaxf(fmaxf(mm[0], mm[1]), fmaxf(mm[2], mm[3]));
    float S2 = ss[0] * fexp2(mm[0] - M2) + ss[1] * fexp2(mm[1] - M2)
             + ss[2] * fexp2(mm[2] - M2) + ss[3] * fexp2(mm[3] - M2);
    float ln = (S2 > 0.f) ? (M2 + flog2(S2)) * LN2F : -INFINITY;

    float sm = fminf(cmins[c], -10.0f * SCALE);   // min(class_min, NEG_FILL)/T, nat domain
    int npad = tot[c] - 1;
    float pt = (npad > 0) ? (logf((float)npad) + sm) : -INFINITY;
    float M = fmaxf(ps_, fmaxf(ln, pt));
    float lse = M + logf(expf(ps_ - M) + expf(ln - M) + expf(pt - M));
    out[b * NPATCH + opos[e]] = lse - ps_;
  }
}

extern "C" void kernel_launch(void* const* d_in, const int* in_sizes, int n_in,
                              void* d_out, int out_size, void* d_ws, size_t ws_size,
                              hipStream_t stream) {
  const float* src = (const float*)d_in[0];
  const float* tgt = (const float*)d_in[1];
  const int* cls   = (const int*)d_in[2];
  float* out = (float*)d_out;

  char* ws = (char*)d_ws;
  unsigned short* tgtb = (unsigned short*)(ws);            // 8,388,608 B
  float* pos = (float*)(ws + 8388608);                     //    65,536 B
  float* pm  = (float*)(ws + 8454144);                     //   262,144 B
  float* ps  = (float*)(ws + 8716288);                     //   262,144 B
  float* pmn = (float*)(ws + 8978432);                     //   262,144 B

  k_cvtpos<<<NROWS / 4, 256, 0, stream>>>(src, tgt, tgtb, pos);
  k_main<<<NBATCH * (NPATCH / BM) * NSPLIT, 256, 0, stream>>>(src, tgtb, cls, pm, ps, pmn);
  k_post<<<NBATCH, 256, 0, stream>>>(cls, pos, pm, ps, pmn, out);
}

// Round 6
// 161.035 us; speedup vs baseline: 1.2891x; 1.0087x over previous
//
#include <hip/hip_runtime.h>
#include <cstdint>

#define NBATCH 4
#define NPATCH 4096
#define MAXC   5
#define BM 64
#define BN 64
#define NSPLIT 8
#define SPLITCOLS (NPATCH / NSPLIT)         /* 512 cols per block */
#define NCIT (SPLITCOLS / BN)               /* 8 col-tiles per block */
#define SCALE  14.285714285714286f          /* 1/T, T=0.07 */
#define SCALE2 20.609929006188747f          /* (1/T) * log2(e) */
#define LN2F   0.6931471805599453f
#define NEGH  -1.0e38f
#define NEGFILL_T -142.85714285714286f      /* NEG_FILL / T */
#define NROWS (NBATCH * NPATCH)
#define SBYTES 16384                        /* one stage buffer: 64 cols x 128 k x 2B */

typedef __attribute__((ext_vector_type(8))) short short8;   // 8 bf16 (4 VGPRs)
typedef __attribute__((ext_vector_type(4))) float f32x4;

__device__ __forceinline__ float fexp2(float x) { return __builtin_amdgcn_exp2f(x); }
__device__ __forceinline__ float flog2(float x) { return __builtin_amdgcn_logf(x); }  // v_log_f32 = log2

__device__ __forceinline__ unsigned short f2bf(float f) {
  uint32_t u = __builtin_bit_cast(uint32_t, f);
  u = (u + 0x7FFFu + ((u >> 16) & 1u)) >> 16;   // RNE
  return (unsigned short)u;
}

// async global -> LDS DMA, 16B per lane; LDS dest = wave-uniform base + lane*16
__device__ __forceinline__ void dma16(const void* g, void* l) {
  __builtin_amdgcn_global_load_lds(
      (const __attribute__((address_space(1))) void*)g,
      (__attribute__((address_space(3))) void*)l, 16, 0, 0);
}

// ---------- fused: tgt f32->bf16 convert + exact f32 positive logits ----------
__global__ __launch_bounds__(256) void k_cvtpos(const float* __restrict__ src,
                                                const float* __restrict__ tgt,
                                                unsigned short* __restrict__ tgtb,
                                                float* __restrict__ pos) {
  int row  = blockIdx.x * 4 + (threadIdx.x >> 6);
  int lane = threadIdx.x & 63;
  float4 va = ((const float4*)src)[(size_t)row * 64 + lane];
  float4 vb = ((const float4*)tgt)[(size_t)row * 64 + lane];
  ushort4 o;
  o.x = f2bf(vb.x); o.y = f2bf(vb.y); o.z = f2bf(vb.z); o.w = f2bf(vb.w);
  ((ushort4*)tgtb)[(size_t)row * 64 + lane] = o;
  float d = va.x * vb.x + va.y * vb.y + va.z * vb.z + va.w * vb.w;
#pragma unroll
  for (int off = 32; off > 0; off >>= 1) d += __shfl_xor(d, off, 64);
  if (lane == 0) pos[row] = d * SCALE;
}

// ---------------- main fused GEMM + online lse stats ----------------
// Linear block map: split = blk&7 == XCD id (HW round-robin) -> XCD-local B slice.
// Double-buffered async DMA staging: stage = 64 cols x K/2, 2 x 16KB LDS.
// XOR chunk swizzle: physical chunk p = logical ^ (col&7), consistent on both sides.
// A fragments pre-scaled by (1/T)*log2e, bf16, in registers for all K=256.
// No row-min tracking (pad term uses NEG_FILL bound; contributes exactly 0 in fp32).
__global__ __launch_bounds__(256) void k_main(const float* __restrict__ src,
                                              const unsigned short* __restrict__ tgtb,
                                              const int* __restrict__ classes,
                                              float* __restrict__ pm,
                                              float* __restrict__ ps) {
  __shared__ uint4 sS[2 * SBYTES / 16];          // 32 KB, two ping-pong stage buffers
  __shared__ int   sCls[SPLITCOLS];              // 2 KB: col classes for this split
  __shared__ float redm[2][BM], reds[2][BM];

  const int blk   = blockIdx.x;
  const int split = blk & (NSPLIT - 1);          // == XCD id under HW round-robin
  const int rbk   = blk >> 3;
  const int b     = rbk >> 6;
  const int rb    = rbk & 63;
  const int rowstart = b * NPATCH + rb * BM;
  const int tid = threadIdx.x;
  const int w = tid >> 6, lane = tid & 63, q = lane >> 4, l4 = lane & 15;
  const int rh = w >> 1, ch = w & 1;
  const int colbase = b * NPATCH + split * SPLITCOLS;

  char* smem = (char*)sS;
  const char* tg8 = (const char*)tgtb;

  // ---- DMA addressing (per lane): inst i covers cols w*16 + r2 + 4i of the stage.
  const int r2  = lane >> 4;
  const int c16 = lane & 15;
  const size_t gbase = (size_t)(colbase + w * 16 + r2) * 512 + (size_t)((c16 ^ r2) * 16);

#define ISSUE(cit_, kh_, bb_)                                                        \
  {                                                                                  \
    _Pragma("unroll")                                                                \
    for (int i = 0; i < 4; ++i) {                                                    \
      size_t g = (gbase + (size_t)(cit_) * 32768 + (size_t)((kh_) * 256) +           \
                  (size_t)(i * 2048)) ^ (size_t)((i & 1) << 6);                      \
      dma16(tg8 + g, smem + (bb_) * SBYTES + w * 4096 + i * 1024);                   \
    }                                                                                \
  }

  // prologue: start DMA for stage (0,0) before the (long) A-fragment setup
  ISSUE(0, 0, 0);

  // col-class preload into LDS (visible after the loop's first barrier)
  sCls[tid]       = classes[colbase + tid];
  sCls[tid + 256] = classes[colbase + 256 + tid];

  // ---- A fragments: f32 -> pre-scaled bf16 once (invariant across col tiles)
  uint4 afr[2][8];
  const float4* s4 = (const float4*)src;
#pragma unroll
  for (int rt = 0; rt < 2; ++rt) {
    int row = rowstart + rh * 32 + rt * 16 + l4;
#pragma unroll
    for (int ks = 0; ks < 8; ++ks) {
      float4 fa = s4[(size_t)row * 64 + ks * 8 + q * 2];
      float4 fb = s4[(size_t)row * 64 + ks * 8 + q * 2 + 1];
      union { ushort4 h[2]; uint4 u; } pk;
      pk.h[0].x = f2bf(fa.x * SCALE2); pk.h[0].y = f2bf(fa.y * SCALE2);
      pk.h[0].z = f2bf(fa.z * SCALE2); pk.h[0].w = f2bf(fa.w * SCALE2);
      pk.h[1].x = f2bf(fb.x * SCALE2); pk.h[1].y = f2bf(fb.y * SCALE2);
      pk.h[1].z = f2bf(fb.z * SCALE2); pk.h[1].w = f2bf(fb.w * SCALE2);
      afr[rt][ks] = pk.u;
    }
  }

  int rcls[2][4];
#pragma unroll
  for (int rt = 0; rt < 2; ++rt)
#pragma unroll
    for (int r = 0; r < 4; ++r)
      rcls[rt][r] = classes[rowstart + rh * 32 + rt * 16 + q * 4 + r];

  float m_[2][4], s_[2][4];
#pragma unroll
  for (int rt = 0; rt < 2; ++rt)
#pragma unroll
    for (int r = 0; r < 4; ++r) { m_[rt][r] = -INFINITY; s_[rt][r] = 0.f; }

  // ---- ds_read addressing: physical chunk = logical ^ (col&7)
  const int kx = (l4 >> 2) & 1;
  const int qq = q ^ (l4 & 3);
  const int bbase0 = (ch * 32 + l4) * 256 + qq * 16;
  const int bbase1 = bbase0 + 4096;              // +16 cols

  int bb = 0;
  for (int cit = 0; cit < NCIT; ++cit) {
    f32x4 acc[2][2];
#pragma unroll
    for (int rt = 0; rt < 2; ++rt)
#pragma unroll
      for (int ct = 0; ct < 2; ++ct) { f32x4 z = {0.f, 0.f, 0.f, 0.f}; acc[rt][ct] = z; }

#pragma unroll
    for (int kh = 0; kh < 2; ++kh) {
      __syncthreads();                           // DMA(cur) landed; prev compute done
      if (kh == 0) {
        ISSUE(cit, 1, bb ^ 1);
      } else if (cit + 1 < NCIT) {
        ISSUE(cit + 1, 0, bb ^ 1);
      }
#pragma unroll
      for (int ksl = 0; ksl < 4; ++ksl) {
        int off = bb * SBYTES + ((ksl ^ kx) << 6);
        short8 b0 = __builtin_bit_cast(short8, *(const uint4*)(smem + off + bbase0));
        short8 b1 = __builtin_bit_cast(short8, *(const uint4*)(smem + off + bbase1));
#pragma unroll
        for (int rt = 0; rt < 2; ++rt) {
          short8 a = __builtin_bit_cast(short8, afr[rt][kh * 4 + ksl]);
          acc[rt][0] = __builtin_amdgcn_mfma_f32_16x16x32_bf16(a, b0, acc[rt][0], 0, 0, 0);
          acc[rt][1] = __builtin_amdgcn_mfma_f32_16x16x32_bf16(a, b1, acc[rt][1], 0, 0, 0);
        }
      }
      bb ^= 1;
    }

    int c0 = sCls[cit * BN + ch * 32 + l4];
    int c1 = sCls[cit * BN + ch * 32 + 16 + l4];

    // online per-lane lse stats, log2 domain (acc pre-scaled), branchless.
#pragma unroll
    for (int rt = 0; rt < 2; ++rt) {
#pragma unroll
      for (int r = 0; r < 4; ++r) {
        int rc = rcls[rt][r];
        float y0 = (c0 == rc) ? NEGH : acc[rt][0][r];
        float y1 = (c1 == rc) ? NEGH : acc[rt][1][r];
        float nm = fmaxf(m_[rt][r], fmaxf(y0, y1));
        float e01 = fexp2(y0 - nm) + fexp2(y1 - nm);
        s_[rt][r] = fmaf(s_[rt][r], fexp2(m_[rt][r] - nm), e01);
        m_[rt][r] = nm;
      }
    }
  }

  // butterfly merge across the 16 col-lanes of each quad
#pragma unroll
  for (int off = 1; off < 16; off <<= 1) {
#pragma unroll
    for (int rt = 0; rt < 2; ++rt)
#pragma unroll
      for (int r = 0; r < 4; ++r) {
        float om = __shfl_xor(m_[rt][r], off, 64);
        float os = __shfl_xor(s_[rt][r], off, 64);
        float nm = fmaxf(m_[rt][r], om);
        s_[rt][r] = s_[rt][r] * fexp2(m_[rt][r] - nm) + os * fexp2(om - nm);
        m_[rt][r] = nm;
      }
  }

  if (l4 == 0) {
#pragma unroll
    for (int rt = 0; rt < 2; ++rt)
#pragma unroll
      for (int r = 0; r < 4; ++r) {
        int li = rh * 32 + rt * 16 + q * 4 + r;
        redm[ch][li] = m_[rt][r];
        reds[ch][li] = s_[rt][r];
      }
  }
  __syncthreads();
  if (tid < BM) {
    float m0 = redm[0][tid], m1 = redm[1][tid];
    float nm = fmaxf(m0, m1);
    float s  = reds[0][tid] * fexp2(m0 - nm) + reds[1][tid] * fexp2(m1 - nm);
    size_t o = (size_t)split * NROWS + rowstart + tid;
    pm[o] = nm;                                   // log2 domain
    ps[o] = s;
  }
#undef ISSUE
}

// ------- fused per-batch scan (counts, stable ranks) + final combine + scatter -------
__global__ __launch_bounds__(256) void k_post(const int* __restrict__ classes,
                                              const float* __restrict__ pos,
                                              const float* __restrict__ pm,
                                              const float* __restrict__ ps,
                                              float* __restrict__ out) {
  __shared__ int sa[MAXC * 256];
  __shared__ int sb2[MAXC * 256];
  int b = blockIdx.x, t = threadIdx.x;
  int base = b * NPATCH + t * 16;
  int cv[16];
#pragma unroll
  for (int e = 0; e < 16; ++e) cv[e] = classes[base + e];
  int cnt[MAXC];
#pragma unroll
  for (int c = 0; c < MAXC; ++c) {
    cnt[c] = 0;
#pragma unroll
    for (int e = 0; e < 16; ++e)
      if (cv[e] == c) cnt[c]++;
  }
#pragma unroll
  for (int c = 0; c < MAXC; ++c) sa[c * 256 + t] = cnt[c];
  __syncthreads();

  int* rp = sa; int* wp = sb2;
  for (int d = 1; d < 256; d <<= 1) {            // Hillis-Steele inclusive scan (8 iters)
#pragma unroll
    for (int c = 0; c < MAXC; ++c) {
      int v = rp[c * 256 + t];
      if (t >= d) v += rp[c * 256 + t - d];
      wp[c * 256 + t] = v;
    }
    __syncthreads();
    int* tmp = rp; rp = wp; wp = tmp;
  }

  int tot[MAXC], excl[MAXC], off[MAXC + 1];
  off[0] = 0;
#pragma unroll
  for (int c = 0; c < MAXC; ++c) {
    tot[c]  = rp[c * 256 + 255];
    excl[c] = rp[c * 256 + t] - cnt[c];
    off[c + 1] = off[c] + tot[c];
  }
  int opos[16];
#pragma unroll
  for (int c = 0; c < MAXC; ++c) {
    int r = off[c] + excl[c];
#pragma unroll
    for (int e = 0; e < 16; ++e)
      if (cv[e] == c) { opos[e] = r; r++; }
  }

  // final combine + scatter for this thread's 16 rows
#pragma unroll
  for (int e = 0; e < 16; ++e) {
    int n = base + e;
    int c = cv[e];
    float ps_ = pos[n];
    float M2 = -INFINITY;
    float mm[NSPLIT], ss[NSPLIT];
#pragma unroll
    for (int s = 0; s < NSPLIT; ++s) {
      mm[s] = pm[(size_t)s * NROWS + n];
      ss[s] = ps[(size_t)s * NROWS + n];
      M2 = fmaxf(M2, mm[s]);
    }
    float S2 = 0.f;
#pragma unroll
    for (int s = 0; s < NSPLIT; ++s) S2 = fmaf(ss[s], fexp2(mm[s] - M2), S2);
    float ln = (S2 > 0.f) ? (M2 + flog2(S2)) * LN2F : -INFINITY;

    // pad term with NEG_FILL bound (exact: true pad term underflows identically)
    int npad = tot[c] - 1;
    float pt = (npad > 0) ? (logf((float)npad) + NEGFILL_T) : -INFINITY;
    float M = fmaxf(ps_, fmaxf(ln, pt));
    float lse = M + logf(expf(ps_ - M) + expf(ln - M) + expf(pt - M));
    out[b * NPATCH + opos[e]] = lse - ps_;
  }
}

extern "C" void kernel_launch(void* const* d_in, const int* in_sizes, int n_in,
                              void* d_out, int out_size, void* d_ws, size_t ws_size,
                              hipStream_t stream) {
  const float* src = (const float*)d_in[0];
  const float* tgt = (const float*)d_in[1];
  const int* cls   = (const int*)d_in[2];
  float* out = (float*)d_out;

  char* ws = (char*)d_ws;
  unsigned short* tgtb = (unsigned short*)(ws);            // 8,388,608 B
  float* pos = (float*)(ws + 8388608);                     //    65,536 B
  float* pm  = (float*)(ws + 8454144);                     //   524,288 B
  float* ps  = (float*)(ws + 8978432);                     //   524,288 B

  k_cvtpos<<<NROWS / 4, 256, 0, stream>>>(src, tgt, tgtb, pos);
  k_main<<<NBATCH * (NPATCH / BM) * NSPLIT, 256, 0, stream>>>(src, tgtb, cls, pm, ps);
  k_post<<<NBATCH, 256, 0, stream>>>(cls, pos, pm, ps, out);
}